// Round 9
// baseline (1755.943 us; speedup 1.0000x reference)
//
#include <hip/hip_runtime.h>
#include <hip/hip_bf16.h>
#include <math.h>

#define B   64
#define T   512
#define E   300
#define H   150
#define G3  450   // 3*H
#define DH  300   // 2*H
#define A   128
#define NC  5
#define NCV 30
#define KP  320   // padded K for E/DH (10 slices of 32)
#define G3P 480   // permuted/padded gate dim: 3 sections of 160
#define LDA 328   // LDS row stride in shorts
#define CHK 64    // T-chunk for the fused xp/gru pipeline

__constant__ int cK0[NC]  = {0,9,12,18,24};
__constant__ int cKC[NC]  = {9,3,6,6,6};
__constant__ int cTS[9]   = {0,3,6,9,12,18,21,24,27};
__constant__ int cTC[9]   = {3,3,3,3,6,3,3,3,3};
__constant__ int cTCAT[9] = {0,0,0,1,2,3,3,4,4};

typedef __attribute__((ext_vector_type(8))) short short8v;
typedef __attribute__((ext_vector_type(4))) short short4v;
typedef __attribute__((ext_vector_type(4))) float f32x4;

__device__ __forceinline__ short f2bf(float v) {
  unsigned u = __builtin_bit_cast(unsigned, v);
  u += 0x7FFFu + ((u >> 16) & 1u);
  return (short)(u >> 16);
}
__device__ __forceinline__ float bf2f(short s) {
  unsigned u = ((unsigned)(unsigned short)s) << 16;
  return __builtin_bit_cast(float, u);
}
// barrier that does NOT drain vmcnt; LDS producer->consumer needs lgkm only.
__device__ __forceinline__ void bar_lgkm() {
  asm volatile("s_waitcnt lgkmcnt(0)" ::: "memory");
  __builtin_amdgcn_s_barrier();
  __builtin_amdgcn_sched_barrier(0);
}
__device__ __forceinline__ float fast_sig(float x) {
  return __builtin_amdgcn_rcpf(1.f + __expf(-x));
}
__device__ __forceinline__ float fast_tanh(float x) {
  x = fminf(fmaxf(x, -15.f), 15.f);
  float ex = __expf(2.f * x);
  return (ex - 1.f) * __builtin_amdgcn_rcpf(ex + 1.f);
}

// ---------------- K0: merged perm + prepx + prepw ----------------
// grid 2048 x 256. block 0: argsort. blocks [1888,2048): prepw (1 wave/row).
// all blocks: prepx grid-stride.
__global__ __launch_bounds__(256) void k_prep(const float* __restrict__ docs,
    const int* __restrict__ len, short* __restrict__ DXH, short* __restrict__ DXL,
    const float* __restrict__ saw, const float* __restrict__ sab,
    const float* __restrict__ gamma, const float* __restrict__ beta,
    short* __restrict__ WGH, short* __restrict__ WGL,
    float* __restrict__ SG, float* __restrict__ CB,
    int* __restrict__ perm, int* __restrict__ Lp) {
  const int tid = threadIdx.x;
  __shared__ int sp[B];
  if (blockIdx.x == 0 && tid < B) {
    int lb = len[tid];
    int rank = 0;
    for (int j = 0; j < B; j++) {
      int lj = len[j];
      rank += (lj > lb) || (lj == lb && j < tid);
    }
    sp[rank] = tid;
  }
  __syncthreads();
  if (blockIdx.x == 0 && tid < B) {
    perm[tid] = sp[tid];
    Lp[tid] = len[sp[tid]];
  }
  if (blockIdx.x >= 1888) {
    const int w = (blockIdx.x - 1888) * 4 + (tid >> 6);
    const int lane = tid & 63;
    if (w < NC * A) {
      const int c = w >> 7;
      const float* wrow = saw + (size_t)w * DH;
      float sg = 0.f, cbv = 0.f;
      for (int e = lane; e < KP; e += 64) {
        float wg = 0.f;
        if (e < DH) {
          float wv = wrow[e];
          wg = wv * gamma[c * DH + e];
          sg += wg;
          cbv += beta[c * DH + e] * wv;
        }
        short hi = f2bf(wg);
        WGH[(size_t)w * KP + e] = hi;
        WGL[(size_t)w * KP + e] = f2bf(wg - bf2f(hi));
      }
#pragma unroll
      for (int off = 32; off; off >>= 1) { sg += __shfl_xor(sg, off); cbv += __shfl_xor(cbv, off); }
      if (lane == 0) { SG[w] = sg; CB[w] = cbv + sab[w]; }
    }
  }
  const int total = B * T * (KP / 8);
  for (int i = blockIdx.x * 256 + tid; i < total; i += 2048 * 256) {
    int bt = i / (KP / 8), q = i - bt * (KP / 8);
    const float* src = docs + (size_t)bt * E + q * 8;
    short8v h{}, l{};
#pragma unroll
    for (int j = 0; j < 8; j++) {
      int e = q * 8 + j;
      float v = (e < E) ? src[j] : 0.f;
      short hi = f2bf(v);
      h[j] = hi; l[j] = f2bf(v - bf2f(hi));
    }
    *(short8v*)(DXH + (size_t)bt * KP + q * 8) = h;
    *(short8v*)(DXL + (size_t)bt * KP + q * 8) = l;
  }
}

// ================= fused XP+GRU kernel (640 threads = 10 waves) =================
// Gate layout PERMUTED+PADDED: sec in {0=r,1=z,2=n}, col = sec*160+u.
// MODE 0: blocks [0,40) GRU(gtbase,XPg); [40,..) XP(xtbase->XPx). MODE 1: XP. MODE 2: GRU.
#define GRU_STEP(TS, CUR, XC)                                                   \
  do {                                                                          \
    short8v ah_[5], al_[5];                                                     \
    _Pragma("unroll") for (int sl = 0; sl < 5; sl++) {                          \
      ah_[sl] = *(const short8v*)&hfH[CUR][l15][sl * 32 + kg * 8];              \
      al_[sl] = *(const short8v*)&hfL[CUR][l15][sl * 32 + kg * 8];              \
    }                                                                           \
    const int tpre = ((TS) + 2 < CHK) ? (TS) + 2 : CHK - 1;                     \
    float xN[3][4];                                                             \
    _Pragma("unroll") for (int sec = 0; sec < 3; sec++)                         \
      _Pragma("unroll") for (int v = 0; v < 4; v++)                             \
        xN[sec][v] = XPg[xbase[v] + (size_t)tpre * G3P + sec * 160];            \
    f32x4 acc[3];                                                               \
    _Pragma("unroll") for (int sec = 0; sec < 3; sec++)                         \
      acc[sec] = f32x4{bias3[sec], bias3[sec], bias3[sec], bias3[sec]};         \
    _Pragma("unroll") for (int sl = 0; sl < 5; sl++) {                          \
      _Pragma("unroll") for (int sec = 0; sec < 3; sec++) {                     \
        acc[sec] = __builtin_amdgcn_mfma_f32_16x16x32_bf16(ah_[sl], Wf[sec][sl], acc[sec], 0, 0, 0); \
        acc[sec] = __builtin_amdgcn_mfma_f32_16x16x32_bf16(al_[sl], Wf[sec][sl], acc[sec], 0, 0, 0); \
      }                                                                         \
    }                                                                           \
    const int t = gtbase + (TS);                                                \
    _Pragma("unroll") for (int v = 0; v < 4; v++) {                             \
      float r = fast_sig(XC[0][v] + acc[0][v]);                                 \
      float z = fast_sig(XC[1][v] + acc[1][v]);                                 \
      float n = fast_tanh(fmaf(r, acc[2][v], XC[2][v]));                        \
      float hnew = fmaf(z, hq[v] - n, n);                                       \
      if (!uLive) hnew = 0.f;                                                   \
      hq[v] = hnew;                                                             \
      short hi = f2bf(hnew); float rem = hnew - bf2f(hi);                       \
      hfH[(CUR) ^ 1][kg * 4 + v][u] = hi;                                       \
      hfL[(CUR) ^ 1][kg * 4 + v][u] = f2bf(rem);                                \
      if (uLive) {                                                              \
        int tout = dir ? ((t < Lq[v]) ? (Lq[v] - 1 - t) : t) : t;               \
        HALL[ho[v] + (size_t)tout * DH] = __float2bfloat16(hnew);               \
      }                                                                         \
    }                                                                           \
    _Pragma("unroll") for (int sec = 0; sec < 3; sec++)                         \
      _Pragma("unroll") for (int v = 0; v < 4; v++) XC[sec][v] = xN[sec][v];    \
    bar_lgkm();                                                                 \
  } while (0)

template<int MODE>
__global__ __launch_bounds__(640, 1) void k_xg(int gtbase, int xtbase,
    const float* __restrict__ XPg, float* __restrict__ XPx,
    const short* __restrict__ DXH, const short* __restrict__ DXL,
    const float* __restrict__ wihf, const float* __restrict__ wihb,
    const float* __restrict__ bihf, const float* __restrict__ bihb,
    const float* __restrict__ whf, const float* __restrict__ whb,
    const float* __restrict__ bhf, const float* __restrict__ bhb,
    const int* __restrict__ perm, const int* __restrict__ Lp,
    __hip_bfloat16* __restrict__ HALL, float* __restrict__ HST) {
  extern __shared__ __align__(16) char smem[];
  const int tid = threadIdx.x, lane = tid & 63, wid = tid >> 6;
  const int l15 = lane & 15, kg = lane >> 4;
  bool isGru; int xpBlk;
  if (MODE == 0) { isGru = (int)blockIdx.x < 40; xpBlk = blockIdx.x - 40; }
  else if (MODE == 1) { isGru = false; xpBlk = blockIdx.x; }
  else { isGru = true; xpBlk = 0; }

  if (!isGru) {
    // XCD-grouped mapping: xcd owns y in {2*xcd, 2*xcd+1}.
    const int xcd = xpBlk & 7, i0 = xpBlk >> 3;          // i0 in [0,60)
    const int y = 2 * xcd + (i0 >= 30 ? 1 : 0);
    const int sn = (i0 >= 30) ? i0 - 30 : i0;
    const int s = sn / 3, nt = sn - (sn / 3) * 3;
    const int c = s >> 1, dir = s & 1;
    const float* W  = (dir ? wihb : wihf) + (size_t)c * G3 * E;
    const float* Bi = (dir ? bihb : bihf) + (size_t)c * G3;
    const int u = wid * 16 + l15;            // 0..159
    const int gwp = nt * 160 + u;
    const bool gv = (u < H);
    const int g = nt * H + u;
    const float biasv = gv ? Bi[g] : 0.f;
    short8v Whi[10], Wlo[10];
#pragma unroll
    for (int sl = 0; sl < 10; sl++) {
      short8v hi{}, lo{};
      if (gv) {
#pragma unroll
        for (int j = 0; j < 8; j++) {
          int k = sl * 32 + kg * 8 + j;
          if (k < E) {
            float w = W[(size_t)g * E + k];
            short h = f2bf(w);
            hi[j] = h; lo[j] = f2bf(w - bf2f(h));
          }
        }
      }
      Whi[sl] = hi; Wlo[sl] = lo;
    }
    short* Ah = (short*)smem;
    short* Al = (short*)(smem + 32 * LDA * 2);
    // T14: register-staged A-tile, loads for it+1 in flight during MFMA of it
    short8v rAh[2], rAl[2];
    {
      const int idx = y * 8;
      const int bb = idx >> 1;
      const int L = Lp[bb];
      const int pb = perm[bb];
      const int t0g = xtbase;
#pragma unroll
      for (int k2 = 0; k2 < 2; k2++) {
        int f = tid + k2 * 640;
        int r = f / 40, q = f - r * 40;
        int tg = t0g + r;
        int src = (dir && tg < L) ? (L - 1 - tg) : tg;
        size_t go = ((size_t)pb * T + src) * KP + q * 8;
        rAh[k2] = *(const short8v*)(DXH + go);
        rAl[k2] = *(const short8v*)(DXL + go);
      }
    }
    for (int it = 0; it < 8; it++) {
      const int idx = y * 8 + it;
      const int bb = idx >> 1, mtile = idx & 1;
      // regs -> LDS
#pragma unroll
      for (int k2 = 0; k2 < 2; k2++) {
        int f = tid + k2 * 640;
        int r = f / 40, q = f - r * 40;
        *(short8v*)&Ah[r * LDA + q * 8] = rAh[k2];
        *(short8v*)&Al[r * LDA + q * 8] = rAl[k2];
      }
      __syncthreads();
      // issue next-iter loads (overlap with MFMA below)
      if (it + 1 < 8) {
        const int idx2 = idx + 1;
        const int b2 = idx2 >> 1, mt2 = idx2 & 1;
        const int L2 = Lp[b2];
        const int pb2 = perm[b2];
        const int t0g2 = xtbase + mt2 * 32;
#pragma unroll
        for (int k2 = 0; k2 < 2; k2++) {
          int f = tid + k2 * 640;
          int r = f / 40, q = f - r * 40;
          int tg = t0g2 + r;
          int src = (dir && tg < L2) ? (L2 - 1 - tg) : tg;
          size_t go = ((size_t)pb2 * T + src) * KP + q * 8;
          rAh[k2] = *(const short8v*)(DXH + go);
          rAl[k2] = *(const short8v*)(DXL + go);
        }
      }
      // 4 independent MFMA chains
      f32x4 acc0[2], acc1[2];
#pragma unroll
      for (int m2 = 0; m2 < 2; m2++) {
        acc0[m2] = f32x4{biasv, biasv, biasv, biasv};
        acc1[m2] = f32x4{0.f, 0.f, 0.f, 0.f};
      }
#pragma unroll
      for (int sl = 0; sl < 10; sl += 2) {
#pragma unroll
        for (int m2 = 0; m2 < 2; m2++) {
          const int ro0 = (m2 * 16 + l15) * LDA + sl * 32 + kg * 8;
          short8v ah0 = *(const short8v*)&Ah[ro0];
          short8v al0 = *(const short8v*)&Al[ro0];
          acc0[m2] = __builtin_amdgcn_mfma_f32_16x16x32_bf16(ah0, Whi[sl], acc0[m2], 0, 0, 0);
          acc0[m2] = __builtin_amdgcn_mfma_f32_16x16x32_bf16(ah0, Wlo[sl], acc0[m2], 0, 0, 0);
          acc0[m2] = __builtin_amdgcn_mfma_f32_16x16x32_bf16(al0, Whi[sl], acc0[m2], 0, 0, 0);
          const int ro1 = ro0 + 32;
          short8v ah1 = *(const short8v*)&Ah[ro1];
          short8v al1 = *(const short8v*)&Al[ro1];
          acc1[m2] = __builtin_amdgcn_mfma_f32_16x16x32_bf16(ah1, Whi[sl + 1], acc1[m2], 0, 0, 0);
          acc1[m2] = __builtin_amdgcn_mfma_f32_16x16x32_bf16(ah1, Wlo[sl + 1], acc1[m2], 0, 0, 0);
          acc1[m2] = __builtin_amdgcn_mfma_f32_16x16x32_bf16(al1, Whi[sl + 1], acc1[m2], 0, 0, 0);
        }
      }
      const size_t base = (size_t)(s * B + bb) * CHK * G3P;
#pragma unroll
      for (int m2 = 0; m2 < 2; m2++) {
        f32x4 acc = acc0[m2] + acc1[m2];
        const int lt = mtile * 32 + m2 * 16 + kg * 4;
        float* xp = XPx + base + (size_t)lt * G3P + gwp;
#pragma unroll
        for (int v = 0; v < 4; v++) xp[(size_t)v * G3P] = acc[v];
      }
      __syncthreads();
    }
    return;
  }

  // -------- GRU body: in-register activation, depth-2 xp prefetch --------
  const int blk = blockIdx.x;         // 0..39
  const int s = blk >> 2, bt = blk & 3;
  const int b0 = bt << 4;
  const int c = s >> 1, dir = s & 1;
  const float* Whh = (dir ? whb : whf) + (size_t)c * G3 * H;
  const float* Bhh = (dir ? bhb : bhf) + (size_t)c * G3;
  short (*hfH)[16][168] = (short(*)[16][168])smem;
  short (*hfL)[16][168] = (short(*)[16][168])(smem + 10752);

  const int u = wid * 16 + l15;
  const bool uLive = (u < H);

  short8v Wf[3][5];
  float bias3[3];
#pragma unroll
  for (int sec = 0; sec < 3; sec++) {
    bias3[sec] = uLive ? Bhh[sec * H + u] : 0.f;
#pragma unroll
    for (int sl = 0; sl < 5; sl++) {
      short8v w = {};
      if (uLive) {
#pragma unroll
        for (int j = 0; j < 8; j++) {
          int k = sl * 32 + kg * 8 + j;
          if (k < H) w[j] = f2bf(Whh[(size_t)(sec * H + u) * H + k]);
        }
      }
      Wf[sec][sl] = w;
    }
  }

  float hq[4];
  int Lq[4];
  size_t xbase[4], ho[4];
#pragma unroll
  for (int v = 0; v < 4; v++) {
    int bg = b0 + kg * 4 + v;
    Lq[v] = Lp[bg];
    xbase[v] = ((size_t)(s * B + bg) * CHK) * G3P + u;
    ho[v] = ((size_t)(c * B + bg) * T) * DH + (size_t)dir * H + u;
    hq[v] = 0.f;
    if (gtbase > 0 && uLive) hq[v] = HST[(size_t)(s * B + bg) * 152 + u];
  }

  for (int f = tid; f < 2 * 16 * 168; f += 640) {
    ((short*)hfH)[f] = 0; ((short*)hfL)[f] = 0;
  }
  __syncthreads();
#pragma unroll
  for (int v = 0; v < 4; v++) {
    short hi = f2bf(hq[v]); float rem = hq[v] - bf2f(hi);
    hfH[0][kg * 4 + v][u] = hi;
    hfL[0][kg * 4 + v][u] = f2bf(rem);
  }
  float xA[3][4], xB[3][4];
#pragma unroll
  for (int sec = 0; sec < 3; sec++)
#pragma unroll
    for (int v = 0; v < 4; v++) {
      xA[sec][v] = XPg[xbase[v] + sec * 160];
      xB[sec][v] = XPg[xbase[v] + (size_t)G3P + sec * 160];
    }
  __syncthreads();

  for (int ts = 0; ts < CHK; ts += 2) {
    GRU_STEP(ts, 0, xA);
    GRU_STEP(ts + 1, 1, xB);
  }
  if (uLive) {
#pragma unroll
    for (int v = 0; v < 4; v++)
      HST[(size_t)(s * B + b0 + kg * 4 + v) * 152 + u] = hq[v];
  }
}

// ---------------- K4: LN-folded MFMA fuse, double-buffered staging ----------------
// grid (512, 5): x = b*8 + oct; 2 t-tiles of 32 rows each.
__global__ __launch_bounds__(512) void k_fuse(const __hip_bfloat16* __restrict__ HALL,
    const short* __restrict__ WGH, const short* __restrict__ WGL,
    const float* __restrict__ SG, const float* __restrict__ CB,
    const float* __restrict__ cvw, float* __restrict__ Ebuf) {
  const int c = blockIdx.y;
  const int b = blockIdx.x >> 3, oct = blockIdx.x & 7;
  const int tid = threadIdx.x, lane = tid & 63, wid = tid >> 6;
  const int l15 = lane & 15, kg = lane >> 4;
  __shared__ short hs[32 * LDA];
  __shared__ float mu_s[32], rs_s[32];
  __shared__ float U_s[32][132];

  const int n = wid * 16 + l15;
  const float sga = SG[c * A + n], cba = CB[c * A + n];
  short8v Wh[10], Wl[10];
#pragma unroll
  for (int sl = 0; sl < 10; sl++) {
    size_t go = ((size_t)(c * A + n)) * KP + sl * 32 + kg * 8;
    Wh[sl] = *(const short8v*)(WGH + go);
    Wl[sl] = *(const short8v*)(WGL + go);
  }
  const int kc = cKC[c], k0c = cK0[c];
  const short* hb0 = (const short*)HALL + ((size_t)(c * B + b) * T + oct * 64) * DH;
  // stage tile 0 directly
  for (int f = tid; f < 32 * 80; f += 512) {
    int r = f / 80, g4 = f - r * 80;
    short4v v{};
    if (g4 < 75) v = *(const short4v*)(hb0 + (size_t)r * DH + g4 * 4);
    *(short4v*)&hs[r * LDA + g4 * 4] = v;
  }
  __syncthreads();
  short4v rg[5];
  for (int tt = 0; tt < 2; tt++) {
    const int t0 = oct * 64 + tt * 32;
    // issue next-tile loads into regs (in flight during stats+MFMA)
    if (tt == 0) {
      const short* hb1 = hb0 + (size_t)32 * DH;
#pragma unroll
      for (int j = 0; j < 5; j++) {
        int f = tid + j * 512;
        int r = f / 80, g4 = f - r * 80;
        rg[j] = (g4 < 75) ? *(const short4v*)(hb1 + (size_t)r * DH + g4 * 4) : short4v{};
      }
    }
    // LN stats (vectorized short8v reads; pad shorts are zero)
    {
      int r = tid >> 4, l = tid & 15;
      float sm = 0.f, sq = 0.f;
      for (int sl8 = l; sl8 < 38; sl8 += 16) {
        short8v v = *(const short8v*)&hs[r * LDA + sl8 * 8];
#pragma unroll
        for (int j = 0; j < 8; j++) { float fv = bf2f(v[j]); sm += fv; sq += fv * fv; }
      }
      sm += __shfl_xor(sm, 1); sm += __shfl_xor(sm, 2); sm += __shfl_xor(sm, 4); sm += __shfl_xor(sm, 8);
      sq += __shfl_xor(sq, 1); sq += __shfl_xor(sq, 2); sq += __shfl_xor(sq, 4); sq += __shfl_xor(sq, 8);
      if (l == 0) {
        float mu = sm * (1.f / 300.f);
        float var = fmaxf(sq * (1.f / 300.f) - mu * mu, 0.f);
        mu_s[r] = mu; rs_s[r] = rsqrtf(var + 1e-5f);
      }
    }
    // MFMA (split hi/lo chains)
    f32x4 acch[2] = {}, accl[2] = {};
#pragma unroll
    for (int sl = 0; sl < 10; sl++) {
#pragma unroll
      for (int m2 = 0; m2 < 2; m2++) {
        short8v ah = *(const short8v*)&hs[(m2 * 16 + l15) * LDA + sl * 32 + kg * 8];
        acch[m2] = __builtin_amdgcn_mfma_f32_16x16x32_bf16(ah, Wh[sl], acch[m2], 0, 0, 0);
        accl[m2] = __builtin_amdgcn_mfma_f32_16x16x32_bf16(ah, Wl[sl], accl[m2], 0, 0, 0);
      }
    }
    __syncthreads();          // hs reads done; mu_s/rs_s visible
    // write staged regs -> hs (next tile)
    if (tt == 0) {
#pragma unroll
      for (int j = 0; j < 5; j++) {
        int f = tid + j * 512;
        int r = f / 80, g4 = f - r * 80;
        *(short4v*)&hs[r * LDA + g4 * 4] = rg[j];
      }
    }
#pragma unroll
    for (int m2 = 0; m2 < 2; m2++) {
      f32x4 acc = acch[m2] + accl[m2];
#pragma unroll
      for (int v = 0; v < 4; v++) {
        int row = m2 * 16 + kg * 4 + v;
        float val = rs_s[row] * acc[v] - mu_s[row] * rs_s[row] * sga + cba;
        U_s[row][n] = fast_tanh(val);
      }
    }
    __syncthreads();          // U_s visible; hs staged
    for (int idx = tid; idx < 32 * kc; idx += 512) {
      int r = idx / kc, kk = idx - r * kc;
      const float* cv = cvw + (size_t)(k0c + kk) * A;
      float e = 0.f;
#pragma unroll 4
      for (int a = 0; a < A; a++) e = fmaf(U_s[r][a], cv[a], e);
      Ebuf[((size_t)(k0c + kk) * B + b) * T + t0 + r] = e;
    }
    __syncthreads();          // U_s free for next tile
  }
}

// ---------------- K5: masked softmax over t per (k,b), in-place ----------------
__global__ __launch_bounds__(256) void k_soft(float* __restrict__ Ebuf,
    const int* __restrict__ Lp) {
  const int k = blockIdx.x >> 6, b = blockIdx.x & 63;
  const int L = Lp[b];
  float* er = Ebuf + ((size_t)k * B + b) * T;
  const int tid = threadIdx.x;
  float v0 = (tid < L) ? er[tid] : -1e30f;
  float v1 = (tid + 256 < L) ? er[tid + 256] : -1e30f;
  float mx = fmaxf(v0, v1);
  __shared__ float red[4];
  __shared__ float red2[4];
#pragma unroll
  for (int off = 32; off; off >>= 1) mx = fmaxf(mx, __shfl_xor(mx, off));
  if ((tid & 63) == 0) red[tid >> 6] = mx;
  __syncthreads();
  mx = fmaxf(fmaxf(red[0], red[1]), fmaxf(red[2], red[3]));
  float e0 = (tid < L) ? __expf(v0 - mx) : 0.f;
  float e1 = (tid + 256 < L) ? __expf(v1 - mx) : 0.f;
  float sm = e0 + e1;
#pragma unroll
  for (int off = 32; off; off >>= 1) sm += __shfl_xor(sm, off);
  if ((tid & 63) == 0) red2[tid >> 6] = sm;
  __syncthreads();
  sm = red2[0] + red2[1] + red2[2] + red2[3];
  const float inv = 1.f / sm;
  er[tid] = e0 * inv;
  er[tid + 256] = e1 * inv;
}

// ---------------- K6: docv partials over t-slices: grid (5, 64, 8) ----------------
__global__ __launch_bounds__(256) void k_docv(const __hip_bfloat16* __restrict__ HALL,
    const float* __restrict__ ATT, float* __restrict__ DOCVP) {
  const int dt = blockIdx.x, b = blockIdx.y, tp = blockIdx.z;
  const int d0 = dt << 6, t0 = tp << 6;
  const int tid = threadIdx.x, tx = tid & 63, ky = tid >> 6;
  const __hip_bfloat16* hb_ = HALL + ((size_t)(4 * B + b) * T + t0) * DH;
  __shared__ float h_s[64][65];
  __shared__ float att_s[30][66];
  float acc[8] = {};
  const int d = d0 + tx;
  for (int f = tid; f < 64 * 64; f += 256) {
    int ttt = f >> 6, dl = f & 63;
    h_s[ttt][dl] = (d0 + dl < DH)
        ? __bfloat162float(hb_[(size_t)ttt * DH + d0 + dl]) : 0.f;
  }
  for (int f = tid; f < 30 * 64; f += 256) {
    int kk = f >> 6, ttt = f & 63;
    att_s[kk][ttt] = ATT[((size_t)kk * B + b) * T + t0 + ttt];
  }
  __syncthreads();
  for (int ttt = 0; ttt < 64; ttt++) {
    float hv = h_s[ttt][tx];
#pragma unroll
    for (int i = 0; i < 8; i++) {
      int kk = ky + (i << 2);
      if (kk < 30) acc[i] = fmaf(att_s[kk][ttt], hv, acc[i]);
    }
  }
  if (d < DH) {
#pragma unroll
    for (int i = 0; i < 8; i++) {
      int kk = ky + (i << 2);
      if (kk < 30)
        DOCVP[((size_t)(tp * NCV + kk) * B + b) * DH + d] = acc[i];
    }
  }
}

// ---------------- reduce 8 docv partials (float4) ----------------
__global__ __launch_bounds__(256) void k_dred(const float* __restrict__ DOCVP,
    float* __restrict__ DOCV) {
  const int n4 = NCV * B * DH / 4;   // 144000
  int i = blockIdx.x * 256 + threadIdx.x;
  if (i < n4) {
    f32x4 s = {};
#pragma unroll
    for (int p = 0; p < 8; p++) s += ((const f32x4*)DOCVP)[(size_t)p * n4 + i];
    ((f32x4*)DOCV)[i] = s;
  }
}

// ---------------- K7: group attention + output ----------------
__global__ __launch_bounds__(64) void k_group(const float* __restrict__ DOCV,
    const float* __restrict__ gaw, const float* __restrict__ gab,
    const float* __restrict__ gcv, float* __restrict__ out) {
  const int tt = blockIdx.x / B, b = blockIdx.x % B;
  const int lane = threadIdx.x;
  const int c = cTCAT[tt], cnt = cTC[tt], ks = cTS[tt];
  const float* wrow = gaw + ((size_t)c * 64 + lane) * DH;
  const float gbias = gab[c * 64 + lane];
  const float cvl = gcv[tt * 64 + lane];
  float accd[5] = {0, 0, 0, 0, 0};
  float wsum = 0.f;
  for (int n = 0; n < cnt; n++) {
    const float* drow = DOCV + ((size_t)(ks + n) * B + b) * DH;
    float g = 0.f;
    for (int dd = 0; dd < DH; dd++) g = fmaf(drow[dd], wrow[dd], g);
    g += gbias;
    float p = g * cvl;
#pragma unroll
    for (int off = 32; off; off >>= 1) p += __shfl_xor(p, off);
    float w = __expf(tanhf(p));
    wsum += w;
#pragma unroll
    for (int i = 0; i < 5; i++) {
      int dd = lane + (i << 6);
      if (dd < DH) accd[i] = fmaf(w, drow[dd], accd[i]);
    }
  }
  const float inv = 1.f / wsum;
  float* orow = out + ((size_t)tt * B + b) * DH;
#pragma unroll
  for (int i = 0; i < 5; i++) {
    int dd = lane + (i << 6);
    if (dd < DH) orow[dd] = accd[i] * inv;
  }
}

extern "C" void kernel_launch(void* const* d_in, const int* in_sizes, int n_in,
                              void* d_out, int out_size, void* d_ws, size_t ws_size,
                              hipStream_t stream) {
  const float* docs = (const float*)d_in[0];
  const int* lens = (const int*)d_in[1];
  const float* wihf = (const float*)d_in[2];
  const float* whhf = (const float*)d_in[3];
  const float* bihf = (const float*)d_in[4];
  const float* bhhf = (const float*)d_in[5];
  const float* wihb = (const float*)d_in[6];
  const float* whhb = (const float*)d_in[7];
  const float* bihb = (const float*)d_in[8];
  const float* bhhb = (const float*)d_in[9];
  const float* gam = (const float*)d_in[10];
  const float* bet = (const float*)d_in[11];
  const float* saw = (const float*)d_in[12];
  const float* sab = (const float*)d_in[13];
  const float* gaw = (const float*)d_in[14];
  const float* gab = (const float*)d_in[15];
  const float* cvw = (const float*)d_in[16];
  const float* gcv = (const float*)d_in[17];
  float* out = (float*)d_out;

  char* ws = (char*)d_ws;
  size_t off = 0;
  auto alloc = [&](size_t bytes) { size_t o = off; off = (off + bytes + 255) & ~(size_t)255; return o; };
  int* PERM = (int*)(ws + alloc(64 * 4));
  int* LP   = (int*)(ws + alloc(64 * 4));
  __hip_bfloat16* HALL = (__hip_bfloat16*)(ws + alloc((size_t)NC * B * T * DH * 2));
  float* EB    = (float*)(ws + alloc((size_t)NCV * B * T * 4));
  float* DOCV  = (float*)(ws + alloc((size_t)NCV * B * DH * 4));
  float* DOCVP = (float*)(ws + alloc((size_t)8 * NCV * B * DH * 4));
  float* HST   = (float*)(ws + alloc((size_t)640 * 152 * 4));
  short* WGH   = (short*)(ws + alloc((size_t)NC * A * KP * 2));
  short* WGL   = (short*)(ws + alloc((size_t)NC * A * KP * 2));
  float* SG    = (float*)(ws + alloc((size_t)NC * A * 4));
  float* CB    = (float*)(ws + alloc((size_t)NC * A * 4));
  short* DXH   = (short*)(ws + alloc((size_t)B * T * KP * 2));
  short* DXL   = (short*)(ws + alloc((size_t)B * T * KP * 2));
  const size_t xpBytes = (size_t)10 * B * CHK * G3P * 4;   // 78.6 MB
  const bool dbuf = (off + 2 * xpBytes + 512) <= ws_size;
  float* XP0 = (float*)(ws + alloc(xpBytes));
  float* XP1 = dbuf ? (float*)(ws + alloc(xpBytes)) : XP0;

  const int DYN = 32 * LDA * 2 * 2;   // 41984 B
  const int NXP = 480;

  hipLaunchKernelGGL(k_prep, dim3(2048), dim3(256), 0, stream,
                     docs, lens, DXH, DXL, saw, sab, gam, bet,
                     WGH, WGL, SG, CB, PERM, LP);
  if (dbuf) {
    k_xg<1><<<dim3(NXP), dim3(640), DYN, stream>>>(0, 0,
        XP0, XP0, DXH, DXL, wihf, wihb, bihf, bihb,
        whhf, whhb, bhhf, bhhb, PERM, LP, HALL, HST);
    for (int j = 0; j < 7; j++) {
      float* g = (j & 1) ? XP1 : XP0;
      float* x = (j & 1) ? XP0 : XP1;
      k_xg<0><<<dim3(40 + NXP), dim3(640), DYN, stream>>>(j * CHK, (j + 1) * CHK,
          g, x, DXH, DXL, wihf, wihb, bihf, bihb,
          whhf, whhb, bhhf, bhhb, PERM, LP, HALL, HST);
    }
    k_xg<2><<<dim3(40), dim3(640), DYN, stream>>>(7 * CHK, 0,
        XP1, XP1, DXH, DXL, wihf, wihb, bihf, bihb,
        whhf, whhb, bhhf, bhhb, PERM, LP, HALL, HST);
  } else {
    for (int j = 0; j < 8; j++) {
      k_xg<1><<<dim3(NXP), dim3(640), DYN, stream>>>(0, j * CHK,
          XP0, XP0, DXH, DXL, wihf, wihb, bihf, bihb,
          whhf, whhb, bhhf, bhhb, PERM, LP, HALL, HST);
      k_xg<2><<<dim3(40), dim3(640), DYN, stream>>>(j * CHK, 0,
          XP0, XP0, DXH, DXL, wihf, wihb, bihf, bihb,
          whhf, whhb, bhhf, bhhb, PERM, LP, HALL, HST);
    }
  }
  hipLaunchKernelGGL(k_fuse, dim3(512, 5), dim3(512), 0, stream,
                     HALL, WGH, WGL, SG, CB, cvw, EB);
  hipLaunchKernelGGL(k_soft, dim3(1920), dim3(256), 0, stream, EB, LP);
  hipLaunchKernelGGL(k_docv, dim3(5, 64, 8), dim3(256), 0, stream, HALL, EB, DOCVP);
  hipLaunchKernelGGL(k_dred, dim3((NCV * B * DH / 4 + 255) / 256), dim3(256), 0, stream,
                     DOCVP, DOCV);
  hipLaunchKernelGGL(k_group, dim3(576), dim3(64), 0, stream, DOCV, gaw, gab, gcv, out);
}